// Round 8
// baseline (142.855 us; speedup 1.0000x reference)
//
#include <hip/hip_runtime.h>
#include <hip/hip_bf16.h>

#define B_SZ  128
#define CH    64
#define T_LEN 4096
#define HID   32
#define INS   3

typedef __attribute__((ext_vector_type(8))) short short8;   // 8 bf16 (4 VGPRs)
typedef __attribute__((ext_vector_type(4))) float f32x4;

__device__ inline unsigned short f2bf_bits(float f) {
  __hip_bfloat16 h = __float2bfloat16(f);
  union { __hip_bfloat16 h; unsigned short u; } cv;
  cv.h = h;
  return cv.u;
}

// ---------------------------------------------------------------------------
// Kernel 1: hypernetwork MLPs. One block per batch sample.
// Emits weight as bf16 in natural [b][o][i] order + fp32 bias.
// ---------------------------------------------------------------------------
__global__ __launch_bounds__(256) void hyper_mlp_kernel(
    const float* __restrict__ z,
    const float* __restrict__ w_w1, const float* __restrict__ w_b1,
    const float* __restrict__ w_g,  const float* __restrict__ w_beta,
    const float* __restrict__ w_w2, const float* __restrict__ w_b2,
    const float* __restrict__ b_w1, const float* __restrict__ b_b1,
    const float* __restrict__ b_g,  const float* __restrict__ b_beta,
    const float* __restrict__ b_w2, const float* __restrict__ b_b2,
    unsigned short* __restrict__ wbf,  // [B][CH_out][CH_in] bf16 bits
    float* __restrict__ bias)          // [B][CH]
{
  const int b   = blockIdx.x;
  const int tid = threadIdx.x;

  __shared__ float zs[INS];
  __shared__ float hraw[2][HID];
  __shared__ float hn[2][HID];

  if (tid < INS) zs[tid] = z[b * INS + tid];
  __syncthreads();

  if (tid < 2 * HID) {
    const int grp = tid >> 5;          // 0 = weight-MLP, 1 = bias-MLP
    const int j   = tid & 31;
    const float* w1 = grp ? b_w1 : w_w1;
    const float* b1 = grp ? b_b1 : w_b1;
    hraw[grp][j] = w1[j*3+0]*zs[0] + w1[j*3+1]*zs[1] + w1[j*3+2]*zs[2] + b1[j];
  }
  __syncthreads();

  if (tid < 2 * HID) {
    const int grp = tid >> 5;
    const int j   = tid & 31;
    float mu = 0.f;
    #pragma unroll
    for (int k = 0; k < HID; ++k) mu += hraw[grp][k];
    mu *= (1.0f / HID);
    float var = 0.f;
    #pragma unroll
    for (int k = 0; k < HID; ++k) { float d = hraw[grp][k] - mu; var += d * d; }
    var *= (1.0f / HID);
    const float r  = rsqrtf(var + 1e-5f);
    const float* g  = grp ? b_g    : w_g;
    const float* be = grp ? b_beta : w_beta;
    const float v = (hraw[grp][j] - mu) * r * g[j] + be[j];
    hn[grp][j] = fmaxf(v, 0.f);
  }
  __syncthreads();

  for (int m = tid; m < CH * CH; m += 256) {
    const float* row = w_w2 + m * HID;
    float acc = w_b2[m];
    #pragma unroll
    for (int i = 0; i < HID; ++i) acc += hn[0][i] * row[i];
    wbf[(size_t)b * CH * CH + m] = f2bf_bits(acc);
  }

  if (tid < CH) {
    const float* row = b_w2 + tid * HID;
    float acc = b_b2[tid];
    #pragma unroll
    for (int i = 0; i < HID; ++i) acc += hn[1][i] * row[i];
    bias[b * CH + tid] = acc;
  }
}

// ---------------------------------------------------------------------------
// Kernel 2: out[b] = W[b] (64x64) @ x[b] (64x4096) + bias, via bf16 MFMA.
// NO LDS, NO barriers. Block = 4 waves; wave owns all 64 o x its own 128 t
// (8 tiles of 16 t). 2-deep software pipeline: all 16 x-loads of tile nt+1
// are issued into the alternate (statically-indexed) buffer BEFORE the
// convert+MFMA of tile nt -> 16 outstanding dwords/wave = 4 KB in flight,
// x16 waves/CU >> Little's-law requirement (~9 KB/CU) -> HBM-BW-bound.
// __launch_bounds__(256,4): <=128 VGPR so the pipeline actually fits in
// registers (round 7's 60-VGPR build serialized the loads).
// ---------------------------------------------------------------------------
__global__ __launch_bounds__(256, 4) void conv1x1_mfma(
    const float* __restrict__ x,
    const unsigned short* __restrict__ wbf,
    const float* __restrict__ bias,
    float* __restrict__ out)
{
  const int b    = blockIdx.y;
  const int tid  = threadIdx.x;
  const int lane = tid & 63;
  const int wid  = tid >> 6;        // 0..3
  const int g    = lane >> 4;       // k-group / row-group
  const int r    = lane & 15;

  const int tbase = blockIdx.x * 512 + wid * 128;

  // A-frags: wbf[b][ot*16 + r][ks*32 + g*8 + 0..7] (16B contiguous)
  const unsigned short* wb = wbf + (size_t)b * CH * CH;
  short8 afrag[4][2];
  #pragma unroll
  for (int ot = 0; ot < 4; ++ot)
    #pragma unroll
    for (int ks = 0; ks < 2; ++ks)
      afrag[ot][ks] = *(const short8*)(wb + (ot * 16 + r) * CH + ks * 32 + g * 8);

  // bias: lane's output rows are o = ot*16 + g*4 + q
  float bv[4][4];
  #pragma unroll
  for (int ot = 0; ot < 4; ++ot)
    #pragma unroll
    for (int q = 0; q < 4; ++q)
      bv[ot][q] = bias[b * CH + ot * 16 + g * 4 + q];

  const float* xl = x   + (size_t)b * CH * T_LEN + (size_t)(g * 8) * T_LEN + tbase + r;
  float*       ol = out + (size_t)b * CH * T_LEN + tbase + r;

  float xbuf[2][16];

  // prologue: issue loads for tile 0
  #pragma unroll
  for (int ks = 0; ks < 2; ++ks)
    #pragma unroll
    for (int j = 0; j < 8; ++j)
      xbuf[0][ks * 8 + j] = xl[(size_t)(ks * 32 + j) * T_LEN];

  #pragma unroll
  for (int nt = 0; nt < 8; ++nt) {
    const int cur = nt & 1;

    // issue next tile's 16 loads into the other buffer (indices all static)
    if (nt < 7) {
      #pragma unroll
      for (int ks = 0; ks < 2; ++ks)
        #pragma unroll
        for (int j = 0; j < 8; ++j)
          xbuf[cur ^ 1][ks * 8 + j] = xl[(size_t)(ks * 32 + j) * T_LEN + (nt + 1) * 16];
    }

    f32x4 acc0 = {bv[0][0], bv[0][1], bv[0][2], bv[0][3]};
    f32x4 acc1 = {bv[1][0], bv[1][1], bv[1][2], bv[1][3]};
    f32x4 acc2 = {bv[2][0], bv[2][1], bv[2][2], bv[2][3]};
    f32x4 acc3 = {bv[3][0], bv[3][1], bv[3][2], bv[3][3]};

    #pragma unroll
    for (int ks = 0; ks < 2; ++ks) {
      union { short8 s; unsigned short u[8]; } bf;
      #pragma unroll
      for (int j = 0; j < 8; ++j) bf.u[j] = f2bf_bits(xbuf[cur][ks * 8 + j]);

      acc0 = __builtin_amdgcn_mfma_f32_16x16x32_bf16(afrag[0][ks], bf.s, acc0, 0, 0, 0);
      acc1 = __builtin_amdgcn_mfma_f32_16x16x32_bf16(afrag[1][ks], bf.s, acc1, 0, 0, 0);
      acc2 = __builtin_amdgcn_mfma_f32_16x16x32_bf16(afrag[2][ks], bf.s, acc2, 0, 0, 0);
      acc3 = __builtin_amdgcn_mfma_f32_16x16x32_bf16(afrag[3][ks], bf.s, acc3, 0, 0, 0);
    }

    // store: out[o = ot*16 + g*4 + q][tbase + nt*16 + r]
    float* os = ol + nt * 16;
    #pragma unroll
    for (int q = 0; q < 4; ++q) {
      os[(size_t)(0 * 16 + g * 4 + q) * T_LEN] = acc0[q];
      os[(size_t)(1 * 16 + g * 4 + q) * T_LEN] = acc1[q];
      os[(size_t)(2 * 16 + g * 4 + q) * T_LEN] = acc2[q];
      os[(size_t)(3 * 16 + g * 4 + q) * T_LEN] = acc3[q];
    }
  }
}

extern "C" void kernel_launch(void* const* d_in, const int* in_sizes, int n_in,
                              void* d_out, int out_size, void* d_ws, size_t ws_size,
                              hipStream_t stream) {
  const float* x      = (const float*)d_in[0];
  const float* z      = (const float*)d_in[1];
  const float* w_w1   = (const float*)d_in[2];
  const float* w_b1   = (const float*)d_in[3];
  const float* w_g    = (const float*)d_in[4];
  const float* w_beta = (const float*)d_in[5];
  const float* w_w2   = (const float*)d_in[6];
  const float* w_b2   = (const float*)d_in[7];
  const float* b_w1   = (const float*)d_in[8];
  const float* b_b1   = (const float*)d_in[9];
  const float* b_g    = (const float*)d_in[10];
  const float* b_beta = (const float*)d_in[11];
  const float* b_w2   = (const float*)d_in[12];
  const float* b_b2   = (const float*)d_in[13];

  float* out = (float*)d_out;
  unsigned short* wbf = (unsigned short*)d_ws;                 // 128*4096 bf16 = 1 MB
  float* bias = (float*)((char*)d_ws + (size_t)B_SZ * CH * CH * sizeof(unsigned short));

  hyper_mlp_kernel<<<B_SZ, 256, 0, stream>>>(
      z, w_w1, w_b1, w_g, w_beta, w_w2, w_b2,
      b_w1, b_b1, b_g, b_beta, b_w2, b_b2, wbf, bias);

  dim3 grid(T_LEN / 512, B_SZ);
  conv1x1_mfma<<<grid, 256, 0, stream>>>(x, wbf, bias, out);
}

// Round 9
// 74.472 us; speedup vs baseline: 1.9182x; 1.9182x over previous
//
#include <hip/hip_runtime.h>
#include <hip/hip_bf16.h>

#define B_SZ  128
#define CH    64
#define T_LEN 4096
#define HID   32
#define INS   3

typedef __attribute__((ext_vector_type(8))) short short8;   // 8 bf16 (4 VGPRs)
typedef __attribute__((ext_vector_type(4))) float f32x4;

__device__ inline unsigned short f2bf_bits(float f) {
  __hip_bfloat16 h = __float2bfloat16(f);
  union { __hip_bfloat16 h; unsigned short u; } cv;
  cv.h = h;
  return cv.u;
}

// ---------------------------------------------------------------------------
// Kernel 1: hypernetwork MLPs. One block per batch sample.
// Emits weight as bf16 in natural [b][o][i] order + fp32 bias.
// ---------------------------------------------------------------------------
__global__ __launch_bounds__(256) void hyper_mlp_kernel(
    const float* __restrict__ z,
    const float* __restrict__ w_w1, const float* __restrict__ w_b1,
    const float* __restrict__ w_g,  const float* __restrict__ w_beta,
    const float* __restrict__ w_w2, const float* __restrict__ w_b2,
    const float* __restrict__ b_w1, const float* __restrict__ b_b1,
    const float* __restrict__ b_g,  const float* __restrict__ b_beta,
    const float* __restrict__ b_w2, const float* __restrict__ b_b2,
    unsigned short* __restrict__ wbf,  // [B][CH_out][CH_in] bf16 bits
    float* __restrict__ bias)          // [B][CH]
{
  const int b   = blockIdx.x;
  const int tid = threadIdx.x;

  __shared__ float zs[INS];
  __shared__ float hraw[2][HID];
  __shared__ float hn[2][HID];

  if (tid < INS) zs[tid] = z[b * INS + tid];
  __syncthreads();

  if (tid < 2 * HID) {
    const int grp = tid >> 5;          // 0 = weight-MLP, 1 = bias-MLP
    const int j   = tid & 31;
    const float* w1 = grp ? b_w1 : w_w1;
    const float* b1 = grp ? b_b1 : w_b1;
    hraw[grp][j] = w1[j*3+0]*zs[0] + w1[j*3+1]*zs[1] + w1[j*3+2]*zs[2] + b1[j];
  }
  __syncthreads();

  if (tid < 2 * HID) {
    const int grp = tid >> 5;
    const int j   = tid & 31;
    float mu = 0.f;
    #pragma unroll
    for (int k = 0; k < HID; ++k) mu += hraw[grp][k];
    mu *= (1.0f / HID);
    float var = 0.f;
    #pragma unroll
    for (int k = 0; k < HID; ++k) { float d = hraw[grp][k] - mu; var += d * d; }
    var *= (1.0f / HID);
    const float r  = rsqrtf(var + 1e-5f);
    const float* g  = grp ? b_g    : w_g;
    const float* be = grp ? b_beta : w_beta;
    const float v = (hraw[grp][j] - mu) * r * g[j] + be[j];
    hn[grp][j] = fmaxf(v, 0.f);
  }
  __syncthreads();

  for (int m = tid; m < CH * CH; m += 256) {
    const float* row = w_w2 + m * HID;
    float acc = w_b2[m];
    #pragma unroll
    for (int i = 0; i < HID; ++i) acc += hn[0][i] * row[i];
    wbf[(size_t)b * CH * CH + m] = f2bf_bits(acc);
  }

  if (tid < CH) {
    const float* row = b_w2 + tid * HID;
    float acc = b_b2[tid];
    #pragma unroll
    for (int i = 0; i < HID; ++i) acc += hn[1][i] * row[i];
    bias[b * CH + tid] = acc;
  }
}

// ---------------------------------------------------------------------------
// Kernel 2: out[b] = W[b] (64x64) @ x[b] (64x4096) + bias, via bf16 MFMA.
// NO LDS, NO barriers. Block = 4 waves; wave owns all 64 o x its own 64 t
// (4 tiles of 16 t). 2-deep software pipeline with TWO NAMED buffers and a
// hand-duplicated schedule (no runtime buffer index -> rule-#20-safe, all
// register): PF A0; PF B1; C A0; PF A2; C B1; PF B3; C A2; C B3.
// 16-32 outstanding dwords/wave (4-8 KB) x 16 waves/CU >> Little's law
// (~17 KB/CU at 6.3 TB/s, ~700ns) -> HBM-BW-bound.
// __launch_bounds__(256,4): 128-VGPR budget so the pipeline fits.
// ---------------------------------------------------------------------------
#define PREFETCH(BUF, NTI)                                           \
  {                                                                  \
    _Pragma("unroll")                                                \
    for (int ks = 0; ks < 2; ++ks) {                                 \
      _Pragma("unroll")                                              \
      for (int j = 0; j < 8; ++j)                                    \
        BUF[ks * 8 + j] = xl[(size_t)(ks * 32 + j) * T_LEN + (NTI) * 16]; \
    }                                                                \
  }

#define COMPUTE(BUF, NTI)                                            \
  {                                                                  \
    f32x4 acc0 = {bv[0][0], bv[0][1], bv[0][2], bv[0][3]};           \
    f32x4 acc1 = {bv[1][0], bv[1][1], bv[1][2], bv[1][3]};           \
    f32x4 acc2 = {bv[2][0], bv[2][1], bv[2][2], bv[2][3]};           \
    f32x4 acc3 = {bv[3][0], bv[3][1], bv[3][2], bv[3][3]};           \
    _Pragma("unroll")                                                \
    for (int ks = 0; ks < 2; ++ks) {                                 \
      union { short8 s; unsigned short u[8]; } bf;                   \
      _Pragma("unroll")                                              \
      for (int j = 0; j < 8; ++j) bf.u[j] = f2bf_bits(BUF[ks * 8 + j]); \
      acc0 = __builtin_amdgcn_mfma_f32_16x16x32_bf16(afrag[0][ks], bf.s, acc0, 0, 0, 0); \
      acc1 = __builtin_amdgcn_mfma_f32_16x16x32_bf16(afrag[1][ks], bf.s, acc1, 0, 0, 0); \
      acc2 = __builtin_amdgcn_mfma_f32_16x16x32_bf16(afrag[2][ks], bf.s, acc2, 0, 0, 0); \
      acc3 = __builtin_amdgcn_mfma_f32_16x16x32_bf16(afrag[3][ks], bf.s, acc3, 0, 0, 0); \
    }                                                                \
    float* os = ol + (NTI) * 16;                                     \
    _Pragma("unroll")                                                \
    for (int q = 0; q < 4; ++q) {                                    \
      os[(size_t)(0 * 16 + g * 4 + q) * T_LEN] = acc0[q];            \
      os[(size_t)(1 * 16 + g * 4 + q) * T_LEN] = acc1[q];            \
      os[(size_t)(2 * 16 + g * 4 + q) * T_LEN] = acc2[q];            \
      os[(size_t)(3 * 16 + g * 4 + q) * T_LEN] = acc3[q];            \
    }                                                                \
  }

__global__ __launch_bounds__(256, 4) void conv1x1_mfma(
    const float* __restrict__ x,
    const unsigned short* __restrict__ wbf,
    const float* __restrict__ bias,
    float* __restrict__ out)
{
  const int b    = blockIdx.y;
  const int tid  = threadIdx.x;
  const int lane = tid & 63;
  const int wid  = tid >> 6;        // 0..3
  const int g    = lane >> 4;       // k-group / row-group
  const int r    = lane & 15;

  const int tbase = blockIdx.x * 256 + wid * 64;

  // A-frags: wbf[b][ot*16 + r][ks*32 + g*8 + 0..7] (16B contiguous)
  const unsigned short* wb = wbf + (size_t)b * CH * CH;
  short8 afrag[4][2];
  #pragma unroll
  for (int ot = 0; ot < 4; ++ot)
    #pragma unroll
    for (int ks = 0; ks < 2; ++ks)
      afrag[ot][ks] = *(const short8*)(wb + (ot * 16 + r) * CH + ks * 32 + g * 8);

  // bias: lane's output rows are o = ot*16 + g*4 + q
  float bv[4][4];
  #pragma unroll
  for (int ot = 0; ot < 4; ++ot)
    #pragma unroll
    for (int q = 0; q < 4; ++q)
      bv[ot][q] = bias[b * CH + ot * 16 + g * 4 + q];

  const float* xl = x   + (size_t)b * CH * T_LEN + (size_t)(g * 8) * T_LEN + tbase + r;
  float*       ol = out + (size_t)b * CH * T_LEN + tbase + r;

  float xa[16], xb[16];

  PREFETCH(xa, 0)
  PREFETCH(xb, 1)
  COMPUTE(xa, 0)
  PREFETCH(xa, 2)
  COMPUTE(xb, 1)
  PREFETCH(xb, 3)
  COMPUTE(xa, 2)
  COMPUTE(xb, 3)
}

extern "C" void kernel_launch(void* const* d_in, const int* in_sizes, int n_in,
                              void* d_out, int out_size, void* d_ws, size_t ws_size,
                              hipStream_t stream) {
  const float* x      = (const float*)d_in[0];
  const float* z      = (const float*)d_in[1];
  const float* w_w1   = (const float*)d_in[2];
  const float* w_b1   = (const float*)d_in[3];
  const float* w_g    = (const float*)d_in[4];
  const float* w_beta = (const float*)d_in[5];
  const float* w_w2   = (const float*)d_in[6];
  const float* w_b2   = (const float*)d_in[7];
  const float* b_w1   = (const float*)d_in[8];
  const float* b_b1   = (const float*)d_in[9];
  const float* b_g    = (const float*)d_in[10];
  const float* b_beta = (const float*)d_in[11];
  const float* b_w2   = (const float*)d_in[12];
  const float* b_b2   = (const float*)d_in[13];

  float* out = (float*)d_out;
  unsigned short* wbf = (unsigned short*)d_ws;                 // 128*4096 bf16 = 1 MB
  float* bias = (float*)((char*)d_ws + (size_t)B_SZ * CH * CH * sizeof(unsigned short));

  hyper_mlp_kernel<<<B_SZ, 256, 0, stream>>>(
      z, w_w1, w_b1, w_g, w_beta, w_w2, w_b2,
      b_w1, b_b1, b_g, b_beta, b_w2, b_b2, wbf, bias);

  dim3 grid(T_LEN / 256, B_SZ);
  conv1x1_mfma<<<grid, 256, 0, stream>>>(x, wbf, bias, out);
}

// Round 10
// 66.033 us; speedup vs baseline: 2.1634x; 1.1278x over previous
//
#include <hip/hip_runtime.h>
#include <hip/hip_bf16.h>

#define B_SZ  128
#define CH    64
#define T_LEN 4096
#define HID   32
#define INS   3

typedef __attribute__((ext_vector_type(8))) short short8;   // 8 bf16 (4 VGPRs)
typedef __attribute__((ext_vector_type(4))) float f32x4;
typedef __attribute__((address_space(1))) const float gfloat1;
typedef __attribute__((address_space(3))) float sfloat3;

__device__ inline unsigned short f2bf_bits(float f) {
  __hip_bfloat16 h = __float2bfloat16(f);
  union { __hip_bfloat16 h; unsigned short u; } cv;
  cv.h = h;
  return cv.u;
}

// ---------------------------------------------------------------------------
// Kernel 1: hypernetwork MLPs. One block per batch sample.
// Emits weight as bf16 in natural [b][o][i] order + fp32 bias.
// ---------------------------------------------------------------------------
__global__ __launch_bounds__(256) void hyper_mlp_kernel(
    const float* __restrict__ z,
    const float* __restrict__ w_w1, const float* __restrict__ w_b1,
    const float* __restrict__ w_g,  const float* __restrict__ w_beta,
    const float* __restrict__ w_w2, const float* __restrict__ w_b2,
    const float* __restrict__ b_w1, const float* __restrict__ b_b1,
    const float* __restrict__ b_g,  const float* __restrict__ b_beta,
    const float* __restrict__ b_w2, const float* __restrict__ b_b2,
    unsigned short* __restrict__ wbf,  // [B][CH_out][CH_in] bf16 bits
    float* __restrict__ bias)          // [B][CH]
{
  const int b   = blockIdx.x;
  const int tid = threadIdx.x;

  __shared__ float zs[INS];
  __shared__ float hraw[2][HID];
  __shared__ float hn[2][HID];

  if (tid < INS) zs[tid] = z[b * INS + tid];
  __syncthreads();

  if (tid < 2 * HID) {
    const int grp = tid >> 5;          // 0 = weight-MLP, 1 = bias-MLP
    const int j   = tid & 31;
    const float* w1 = grp ? b_w1 : w_w1;
    const float* b1 = grp ? b_b1 : w_b1;
    hraw[grp][j] = w1[j*3+0]*zs[0] + w1[j*3+1]*zs[1] + w1[j*3+2]*zs[2] + b1[j];
  }
  __syncthreads();

  if (tid < 2 * HID) {
    const int grp = tid >> 5;
    const int j   = tid & 31;
    float mu = 0.f;
    #pragma unroll
    for (int k = 0; k < HID; ++k) mu += hraw[grp][k];
    mu *= (1.0f / HID);
    float var = 0.f;
    #pragma unroll
    for (int k = 0; k < HID; ++k) { float d = hraw[grp][k] - mu; var += d * d; }
    var *= (1.0f / HID);
    const float r  = rsqrtf(var + 1e-5f);
    const float* g  = grp ? b_g    : w_g;
    const float* be = grp ? b_beta : w_beta;
    const float v = (hraw[grp][j] - mu) * r * g[j] + be[j];
    hn[grp][j] = fmaxf(v, 0.f);
  }
  __syncthreads();

  for (int m = tid; m < CH * CH; m += 256) {
    const float* row = w_w2 + m * HID;
    float acc = w_b2[m];
    #pragma unroll
    for (int i = 0; i < HID; ++i) acc += hn[0][i] * row[i];
    wbf[(size_t)b * CH * CH + m] = f2bf_bits(acc);
  }

  if (tid < CH) {
    const float* row = b_w2 + tid * HID;
    float acc = b_b2[tid];
    #pragma unroll
    for (int i = 0; i < HID; ++i) acc += hn[1][i] * row[i];
    bias[b * CH + tid] = acc;
  }
}

// ---------------------------------------------------------------------------
// Kernel 2: out[b] = W[b] (64x64) @ x[b] (64x4096) + bias via bf16 MFMA,
// x staged through LDS with global_load_lds (in-flight bytes live in the
// vmcnt queue, NOT VGPRs -- hipcc kept defeating register pipelines).
// Block = 4 waves, one (b, 256-t tile). x tile = 4 t-chunks [64 k][64 t]
// (16.25 KB each; 4-row groups with 1040 B stride -> ds_read 2-way = free).
// Counted-vmcnt pipeline, never drained (T3/T4): STAGE 0,1,2; wait(8) bar;
// STAGE 3; COMP0; wait(24) bar; COMP1; wait(36) bar; COMP2; wait(48) bar;
// COMP3. Waits are exact in-order ledgers incl. 12 afrag/bias loads and 16
// stores per COMP; chunk slots are never reused -> no WAR barriers needed.
// ---------------------------------------------------------------------------
#define STAGE(C)                                                              \
  {                                                                           \
    _Pragma("unroll")                                                         \
    for (int q = 0; q < 4; ++q) {                                             \
      const int m = wid * 4 + q;                                              \
      const float* ga = xb + (size_t)(4 * m + rowin) * T_LEN + (C) * 64 + col4; \
      __builtin_amdgcn_global_load_lds((gfloat1*)ga,                          \
          (sfloat3*)(lds + (C) * 4160 + m * 260), 16, 0, 0);                  \
    }                                                                         \
  }

#define COMPUTE(C)                                                            \
  {                                                                           \
    f32x4 a0 = {bv[0][0], bv[0][1], bv[0][2], bv[0][3]};                      \
    f32x4 a1 = {bv[1][0], bv[1][1], bv[1][2], bv[1][3]};                      \
    f32x4 a2 = {bv[2][0], bv[2][1], bv[2][2], bv[2][3]};                      \
    f32x4 a3 = {bv[3][0], bv[3][1], bv[3][2], bv[3][3]};                      \
    _Pragma("unroll")                                                         \
    for (int ks = 0; ks < 2; ++ks) {                                          \
      union { short8 s; unsigned short u[8]; } bfv;                           \
      _Pragma("unroll")                                                       \
      for (int j = 0; j < 8; ++j) {                                           \
        const float f = lds[(C) * 4160 + (ks * 8 + g * 2 + (j >> 2)) * 260    \
                            + (j & 3) * 64 + tloc];                           \
        bfv.u[j] = f2bf_bits(f);                                              \
      }                                                                       \
      a0 = __builtin_amdgcn_mfma_f32_16x16x32_bf16(afrag[0][ks], bfv.s, a0, 0, 0, 0); \
      a1 = __builtin_amdgcn_mfma_f32_16x16x32_bf16(afrag[1][ks], bfv.s, a1, 0, 0, 0); \
      a2 = __builtin_amdgcn_mfma_f32_16x16x32_bf16(afrag[2][ks], bfv.s, a2, 0, 0, 0); \
      a3 = __builtin_amdgcn_mfma_f32_16x16x32_bf16(afrag[3][ks], bfv.s, a3, 0, 0, 0); \
    }                                                                         \
    float* os = op + (C) * 64;                                                \
    _Pragma("unroll")                                                         \
    for (int q = 0; q < 4; ++q) {                                             \
      os[(size_t)(0 * 16 + g * 4 + q) * T_LEN] = a0[q];                       \
      os[(size_t)(1 * 16 + g * 4 + q) * T_LEN] = a1[q];                       \
      os[(size_t)(2 * 16 + g * 4 + q) * T_LEN] = a2[q];                       \
      os[(size_t)(3 * 16 + g * 4 + q) * T_LEN] = a3[q];                       \
    }                                                                         \
  }

#define WAITB(N)                                                              \
  {                                                                           \
    asm volatile("s_waitcnt vmcnt(" #N ")" ::: "memory");                     \
    __builtin_amdgcn_s_barrier();                                             \
    asm volatile("" ::: "memory");                                            \
  }

__global__ __launch_bounds__(256, 4) void conv1x1_mfma(
    const float* __restrict__ x,
    const unsigned short* __restrict__ wbf,
    const float* __restrict__ bias,
    float* __restrict__ out)
{
  __shared__ __align__(16) float lds[4 * 4160];   // 66560 B

  const int b     = blockIdx.y;
  const int tbi   = blockIdx.x;
  const int tid   = threadIdx.x;
  const int lane  = tid & 63;
  const int wid   = tid >> 6;       // 0..3 (uniform per wave)
  const int g     = lane >> 4;      // 16-lane group
  const int r     = lane & 15;
  const int rowin = lane >> 4;      // staging row-in-group
  const int col4  = (lane & 15) * 4;
  const int tloc  = wid * 16 + r;   // t within chunk

  // A-frags: wbf[b][ot*16 + r][ks*32 + g*8 + 0..7]  (8 x 16B loads)
  const unsigned short* wb = wbf + (size_t)b * CH * CH;
  short8 afrag[4][2];
  #pragma unroll
  for (int ot = 0; ot < 4; ++ot)
    #pragma unroll
    for (int ks = 0; ks < 2; ++ks)
      afrag[ot][ks] = *(const short8*)(wb + (ot * 16 + r) * CH + ks * 32 + g * 8);

  // bias for lane's output rows o = ot*16 + g*4 + q  (4 x 16B loads)
  float bv[4][4];
  #pragma unroll
  for (int ot = 0; ot < 4; ++ot) {
    const float4 t = *(const float4*)(bias + b * CH + ot * 16 + g * 4);
    bv[ot][0] = t.x; bv[ot][1] = t.y; bv[ot][2] = t.z; bv[ot][3] = t.w;
  }

  const float* xb = x   + (size_t)b * CH * T_LEN + tbi * 256;
  float*       op = out + (size_t)b * CH * T_LEN + tbi * 256 + tloc;

  STAGE(0)
  STAGE(1)
  STAGE(2)

  WAITB(8)           // A(12)+L0 retired; L1,L2 (8) may remain in flight
  STAGE(3)
  asm volatile("" ::: "memory");   // pin L3 issue before COMP0's stores
  COMPUTE(0)

  WAITB(24)          // L1 retired; L2+L3+S0 (24) may remain
  COMPUTE(1)

  WAITB(36)          // L2 retired; L3+S0+S1 (36) may remain
  COMPUTE(2)

  WAITB(48)          // L3 retired; S0+S1+S2 (48) may remain
  COMPUTE(3)
}

extern "C" void kernel_launch(void* const* d_in, const int* in_sizes, int n_in,
                              void* d_out, int out_size, void* d_ws, size_t ws_size,
                              hipStream_t stream) {
  const float* x      = (const float*)d_in[0];
  const float* z      = (const float*)d_in[1];
  const float* w_w1   = (const float*)d_in[2];
  const float* w_b1   = (const float*)d_in[3];
  const float* w_g    = (const float*)d_in[4];
  const float* w_beta = (const float*)d_in[5];
  const float* w_w2   = (const float*)d_in[6];
  const float* w_b2   = (const float*)d_in[7];
  const float* b_w1   = (const float*)d_in[8];
  const float* b_b1   = (const float*)d_in[9];
  const float* b_g    = (const float*)d_in[10];
  const float* b_beta = (const float*)d_in[11];
  const float* b_w2   = (const float*)d_in[12];
  const float* b_b2   = (const float*)d_in[13];

  float* out = (float*)d_out;
  unsigned short* wbf = (unsigned short*)d_ws;                 // 128*4096 bf16 = 1 MB
  float* bias = (float*)((char*)d_ws + (size_t)B_SZ * CH * CH * sizeof(unsigned short));

  hyper_mlp_kernel<<<B_SZ, 256, 0, stream>>>(
      z, w_w1, w_b1, w_g, w_beta, w_w2, w_b2,
      b_w1, b_b1, b_g, b_beta, b_w2, b_b2, wbf, bias);

  dim3 grid(T_LEN / 256, B_SZ);
  conv1x1_mfma<<<grid, 256, 0, stream>>>(x, wbf, bias, out);
}